// Round 3
// baseline (3743.867 us; speedup 1.0000x reference)
//
#include <hip/hip_runtime.h>
#include <math.h>

#define HID 256
#define BM 128
#define BN 128
#define BK 16

__device__ __forceinline__ float sigmoidf_(float x){ return 1.0f/(1.0f + __expf(-x)); }

// ---- edge index access: handles both int32 and int64 on-disk storage ----
__device__ __forceinline__ int edge_src(const int* ei, int e, int is64){
  return is64 ? ei[2*e] : ei[e];
}
__device__ __forceinline__ int edge_dst(const int* ei, int e, int E, int is64){
  return is64 ? ei[2*(E+e)] : ei[E+e];
}

__global__ void detect_kernel(const int* __restrict__ ei, int* __restrict__ flag){
  __shared__ int any;
  if (threadIdx.x == 0) any = 0;
  __syncthreads();
  if (ei[2*threadIdx.x + 1] != 0) atomicOr(&any, 1);
  __syncthreads();
  if (threadIdx.x == 0) *flag = any ? 0 : 1;   // 1 -> int64 storage
}

__global__ void count_kernel(const int* __restrict__ ei, const int* __restrict__ flag,
                             int* __restrict__ deg_i, int E){
  int e = blockIdx.x*blockDim.x + threadIdx.x;
  if (e >= E) return;
  int is64 = *flag;
  atomicAdd(&deg_i[edge_dst(ei,e,E,is64)], 1);
}

__global__ __launch_bounds__(1024) void scan_kernel(const int* __restrict__ deg_i,
  int* __restrict__ row_ptr, float* __restrict__ inv_deg, int N)
{
  __shared__ int wsum[16];
  __shared__ int carry_s;
  int tid = threadIdx.x, lane = tid & 63, wid = tid >> 6;
  if (tid == 0) carry_s = 0;
  __syncthreads();
  for (int base = 0; base < N; base += 1024){
    int i = base + tid;
    int v = (i < N) ? deg_i[i] : 0;
    int s = v;
    #pragma unroll
    for (int off = 1; off < 64; off <<= 1){
      int t = __shfl_up(s, off, 64);
      if (lane >= off) s += t;
    }
    if (lane == 63) wsum[wid] = s;
    __syncthreads();
    if (tid == 0){
      int run = 0;
      for (int w2 = 0; w2 < 16; ++w2){ int t = wsum[w2]; wsum[w2] = run; run += t; }
    }
    __syncthreads();
    int excl = carry_s + wsum[wid] + s - v;
    if (i < N){
      row_ptr[i] = excl;
      inv_deg[i] = 1.0f / fmaxf((float)v, 1.0f);
    }
    __syncthreads();
    if (tid == 1023) carry_s = excl + v;
    __syncthreads();
  }
  if (threadIdx.x == 0) row_ptr[N] = carry_s;
}

__global__ void fill_kernel(const int* __restrict__ ei, const int* __restrict__ flag,
                            const int* __restrict__ row_ptr, int* __restrict__ cursor,
                            int* __restrict__ col_src, int E){
  int e = blockIdx.x*blockDim.x + threadIdx.x;
  if (e >= E) return;
  int is64 = *flag;
  int d = edge_dst(ei,e,E,is64);
  int pos = atomicAdd(&cursor[d], 1);
  col_src[row_ptr[d] + pos] = edge_src(ei,e,is64);
}

// mean aggregation: one wave per node, float4 per lane (64*4 = 256 dims)
__global__ __launch_bounds__(256) void aggregate_kernel(
    const float* __restrict__ X, float* __restrict__ out,
    const int* __restrict__ row_ptr, const int* __restrict__ col_src,
    const float* __restrict__ inv_deg, int N)
{
  int v = blockIdx.x*4 + (threadIdx.x >> 6);
  int lane = threadIdx.x & 63;
  if (v >= N) return;
  int beg = row_ptr[v], end = row_ptr[v+1];
  float ax=0.f, ay=0.f, az=0.f, aw=0.f;
  int e = beg;
  for (; e + 4 <= end; e += 4){
    int s0 = col_src[e], s1 = col_src[e+1], s2 = col_src[e+2], s3 = col_src[e+3];
    float4 a = *(const float4*)&X[(size_t)s0*HID + lane*4];
    float4 b = *(const float4*)&X[(size_t)s1*HID + lane*4];
    float4 c = *(const float4*)&X[(size_t)s2*HID + lane*4];
    float4 d = *(const float4*)&X[(size_t)s3*HID + lane*4];
    ax += a.x+b.x+c.x+d.x; ay += a.y+b.y+c.y+d.y;
    az += a.z+b.z+c.z+d.z; aw += a.w+b.w+c.w+d.w;
  }
  for (; e < end; ++e){
    int s0 = col_src[e];
    float4 a = *(const float4*)&X[(size_t)s0*HID + lane*4];
    ax += a.x; ay += a.y; az += a.z; aw += a.w;
  }
  float w = inv_deg[v];
  float4 r; r.x = ax*w; r.y = ay*w; r.z = az*w; r.w = aw*w;
  *(float4*)&out[(size_t)v*HID + lane*4] = r;
}

// layer-1 constant rows: hrow = tanh(bb1+bb2+bh0@Wb2); rowL/rowR for r,z
__global__ __launch_bounds__(256) void rowprep_kernel(
  const float* __restrict__ bh_l, const float* __restrict__ bb1, const float* __restrict__ bb2,
  const float* __restrict__ Wb2, const float* __restrict__ Wh_l, const float* __restrict__ Wh_r,
  float* __restrict__ hrow, float* __restrict__ rowL1, float* __restrict__ rowR1,
  float* __restrict__ rowL2, float* __restrict__ rowR2)
{
  __shared__ float sh[256];
  __shared__ float sh2[256];
  int j = threadIdx.x;
  sh[j] = bh_l[j];                       // bh_l[0]
  __syncthreads();
  float acc = bb1[j] + bb2[j];
  for (int k = 0; k < 256; ++k) acc = fmaf(sh[k], Wb2[k*256 + j], acc);
  float hr = tanhf(acc);
  hrow[j] = hr; sh2[j] = hr;
  __syncthreads();
  const float* Whl1 = Wh_l + 65536;  const float* Whr1 = Wh_r + 65536;
  const float* Whl2 = Wh_l + 131072; const float* Whr2 = Wh_r + 131072;
  float a1=0.f, b1=0.f, a2=0.f, b2v=0.f;
  for (int k = 0; k < 256; ++k){
    float hv = sh2[k];
    a1  = fmaf(hv, Whl1[k*256+j], a1);
    b1  = fmaf(hv, Whr1[k*256+j], b1);
    a2  = fmaf(hv, Whl2[k*256+j], a2);
    b2v = fmaf(hv, Whr2[k*256+j], b2v);
  }
  rowL1[j] = a1; rowR1[j] = b1 + bh_l[256 + j];
  rowL2[j] = a2; rowR2[j] = b2v + bh_l[512 + j];
}

// out = epilogue(sum_i Ai@Wi + bias + bias2)
// MODE 0 LIN: pre
// MODE 1 SIG: sigmoid(pre + g*rowA + rowB) * mulrow * mulmat (each optional)
// MODE 2 TANHADD: HN[idx] + tanh(pre)
// MODE 3 GRU: (1-Z)*HN + Z*tanh(pre), HN row-broadcast if hn_bcast
template<int MODE>
__global__ __launch_bounds__(256) void gemm_kernel(
    const float* __restrict__ A0, const float* __restrict__ W0,
    const float* __restrict__ A1, const float* __restrict__ W1,
    const float* __restrict__ A2, const float* __restrict__ W2,
    const float* __restrict__ A3, const float* __restrict__ W3,
    const float* __restrict__ bias, const float* __restrict__ bias2,
    const float* __restrict__ Z, const float* __restrict__ HN, int hn_bcast,
    const float* __restrict__ rowA, const float* __restrict__ rowB,
    const float* __restrict__ mulrow, const float* __restrict__ mulmat,
    const int* __restrict__ deg,
    float* __restrict__ out, int M)
{
  __shared__ float As[BK][BM+4];
  __shared__ float Ws[BK][BN];
  const int tid = threadIdx.x;
  const int tx = tid & 15, ty = tid >> 4;
  const int row0 = blockIdx.x * BM, col0 = blockIdx.y * BN;
  float acc[8][8];
  #pragma unroll
  for (int i = 0; i < 8; ++i)
    #pragma unroll
    for (int j = 0; j < 8; ++j) acc[i][j] = 0.f;

  const float* Ap_[4] = {A0, A1, A2, A3};
  const float* Wp_[4] = {W0, W1, W2, W3};
  #pragma unroll
  for (int pass = 0; pass < 4; ++pass){
    const float* Ap = Ap_[pass];
    const float* Wp = Wp_[pass];
    if (Ap == nullptr) continue;           // uniform across grid
    for (int k0 = 0; k0 < HID; k0 += BK){
      #pragma unroll
      for (int it = 0; it < 2; ++it){
        int idx = tid + it*256;            // 0..511
        int r = idx >> 2, q = idx & 3;
        int gr = row0 + r; if (gr > M-1) gr = M-1;
        float4 av = *(const float4*)&Ap[(size_t)gr*HID + k0 + q*4];
        As[q*4+0][r] = av.x; As[q*4+1][r] = av.y;
        As[q*4+2][r] = av.z; As[q*4+3][r] = av.w;
      }
      #pragma unroll
      for (int it = 0; it < 2; ++it){
        int idx = tid + it*256;
        int kk = idx >> 5, c4 = idx & 31;
        *(float4*)&Ws[kk][c4*4] = *(const float4*)&Wp[(size_t)(k0+kk)*HID + col0 + c4*4];
      }
      __syncthreads();
      #pragma unroll
      for (int k = 0; k < BK; ++k){
        float a[8], w[8];
        *(float4*)(a)   = *(const float4*)&As[k][ty*8];
        *(float4*)(a+4) = *(const float4*)&As[k][ty*8+4];
        *(float4*)(w)   = *(const float4*)&Ws[k][tx*4];
        *(float4*)(w+4) = *(const float4*)&Ws[k][tx*4+64];
        #pragma unroll
        for (int i = 0; i < 8; ++i)
          #pragma unroll
          for (int j = 0; j < 8; ++j) acc[i][j] = fmaf(a[i], w[j], acc[i][j]);
      }
      __syncthreads();
    }
  }

  #pragma unroll
  for (int i = 0; i < 8; ++i){
    int gr = row0 + ty*8 + i;
    if (gr >= M) break;
    float gd = 0.f;
    if (MODE == 1 && deg != nullptr) gd = (deg[gr] > 0) ? 1.f : 0.f;
    #pragma unroll
    for (int half = 0; half < 2; ++half){
      int gc = col0 + half*64 + tx*4;
      size_t idx = (size_t)gr*HID + gc;
      float4 o;
      #pragma unroll
      for (int c = 0; c < 4; ++c){
        float p = acc[i][half*4 + c];
        if (bias)  p += bias[gc + c];
        if (bias2) p += bias2[gc + c];
        float r;
        if (MODE == 0) r = p;
        else if (MODE == 1){
          float add = rowA ? (gd*rowA[gc + c] + rowB[gc + c]) : 0.f;
          r = sigmoidf_(p + add);
          if (mulrow) r *= mulrow[gc + c];
          if (mulmat) r *= mulmat[idx + c];
        }
        else if (MODE == 2) r = HN[idx + c] + tanhf(p);
        else {
          float z  = Z[idx + c];
          float hv = hn_bcast ? HN[gc + c] : HN[idx + c];
          r = (1.f - z)*hv + z*tanhf(p);
        }
        (&o.x)[c] = r;
      }
      *(float4*)&out[idx] = o;
    }
  }
}

// per-edge: preds = sigmoid(relu(P[s]+Q[d]) . We2 + be2); be1 folded into P
__global__ __launch_bounds__(256) void edge_pred_kernel(
  const float* __restrict__ P, const float* __restrict__ Q,
  const int* __restrict__ ei, const int* __restrict__ flag,
  const float* __restrict__ We2, const float* __restrict__ be2,
  float* __restrict__ preds, int E)
{
  int wid = blockIdx.x*4 + (threadIdx.x >> 6);
  int lane = threadIdx.x & 63;
  if (wid >= E) return;
  int is64 = *flag;
  int s = edge_src(ei, wid, is64);
  int d = edge_dst(ei, wid, E, is64);
  float4 p = *(const float4*)&P[(size_t)s*HID + lane*4];
  float4 q = *(const float4*)&Q[(size_t)d*HID + lane*4];
  float4 w = *(const float4*)&We2[lane*4];
  float h0 = fmaxf(p.x + q.x, 0.f), h1 = fmaxf(p.y + q.y, 0.f);
  float h2 = fmaxf(p.z + q.z, 0.f), h3 = fmaxf(p.w + q.w, 0.f);
  float part = h0*w.x + h1*w.y + h2*w.z + h3*w.w;
  #pragma unroll
  for (int off = 32; off > 0; off >>= 1) part += __shfl_down(part, off, 64);
  if (lane == 0) preds[wid] = sigmoidf_(part + be2[0]);
}

static void launch_gemm(int mode,
  const float* A0, const float* W0, const float* A1, const float* W1,
  const float* A2, const float* W2, const float* A3, const float* W3,
  const float* bias, const float* bias2,
  const float* Z, const float* HN, int hn_bcast,
  const float* rowA, const float* rowB,
  const float* mulrow, const float* mulmat, const int* deg,
  float* out, int M, hipStream_t s)
{
  dim3 g((M + BM - 1)/BM, HID/BN), b(256);
  switch (mode){
    case 0: gemm_kernel<0><<<g,b,0,s>>>(A0,W0,A1,W1,A2,W2,A3,W3,bias,bias2,Z,HN,hn_bcast,rowA,rowB,mulrow,mulmat,deg,out,M); break;
    case 1: gemm_kernel<1><<<g,b,0,s>>>(A0,W0,A1,W1,A2,W2,A3,W3,bias,bias2,Z,HN,hn_bcast,rowA,rowB,mulrow,mulmat,deg,out,M); break;
    case 2: gemm_kernel<2><<<g,b,0,s>>>(A0,W0,A1,W1,A2,W2,A3,W3,bias,bias2,Z,HN,hn_bcast,rowA,rowB,mulrow,mulmat,deg,out,M); break;
    default:gemm_kernel<3><<<g,b,0,s>>>(A0,W0,A1,W1,A2,W2,A3,W3,bias,bias2,Z,HN,hn_bcast,rowA,rowB,mulrow,mulmat,deg,out,M); break;
  }
}

extern "C" void kernel_launch(void* const* d_in, const int* in_sizes, int n_in,
                              void* d_out, int out_size, void* d_ws, size_t ws_size,
                              hipStream_t stream)
{
  const float* x    = (const float*)d_in[0];
  const int*   ei   = (const int*)  d_in[1];
  const float* Wx_l = (const float*)d_in[2];
  const float* bx_l = (const float*)d_in[3];
  const float* Wx_r = (const float*)d_in[4];
  const float* Wh_l = (const float*)d_in[5];
  const float* bh_l = (const float*)d_in[6];
  const float* Wh_r = (const float*)d_in[7];
  const float* Wb1  = (const float*)d_in[8];
  const float* bb1  = (const float*)d_in[9];
  const float* Wb2  = (const float*)d_in[10];
  const float* bb2  = (const float*)d_in[11];
  const float* We1  = (const float*)d_in[12];
  const float* be1  = (const float*)d_in[13];
  const float* We2  = (const float*)d_in[14];
  const float* be2  = (const float*)d_in[15];

  const int N = in_sizes[0] / HID;
  const int E = in_sizes[1] / 2;
  const float* NUL  = nullptr;
  const int*   NULI = nullptr;

  size_t off = 0;
  auto alloc = [&](size_t bytes) -> void* {
    void* p = (char*)d_ws + off;
    off += (bytes + 255) & ~(size_t)255;
    return p;
  };
  int*   deg_i   = (int*)  alloc((size_t)N*4);
  int*   cursor  = (int*)  alloc((size_t)N*4);
  int*   row_ptr = (int*)  alloc(((size_t)N+1)*4);
  int*   col_src = (int*)  alloc((size_t)E*4);
  float* inv_deg = (float*)alloc((size_t)N*4);
  int*   flag    = (int*)  alloc(256);
  float* hrow    = (float*)alloc(1024);
  float* rowL1   = (float*)alloc(1024);
  float* rowR1   = (float*)alloc(1024);
  float* rowL2   = (float*)alloc(1024);
  float* rowR2   = (float*)alloc(1024);
  float* B0 = (float*)alloc((size_t)N*HID*4);
  float* B1 = (float*)alloc((size_t)N*HID*4);
  float* B2 = (float*)alloc((size_t)N*HID*4);
  float* B3 = (float*)alloc((size_t)N*HID*4);

  float* preds = (float*)d_out;
  float* H     = preds + E;          // final h2 lives here; used as scratch before

  // weight slices
  const float* Wxl0 = Wx_l;          const float* Wxr0 = Wx_r;
  const float* Wxl1 = Wx_l + 65536;  const float* Wxr1 = Wx_r + 65536;
  const float* Wxl2 = Wx_l + 131072; const float* Wxr2 = Wx_r + 131072;
  const float* Whl0 = Wh_l;          const float* Whr0 = Wh_r;
  const float* Whl1 = Wh_l + 65536;  const float* Whr1 = Wh_r + 65536;
  const float* Whl2 = Wh_l + 131072; const float* Whr2 = Wh_r + 131072;
  const float* Whl3 = Wh_l + 196608; const float* Whr3 = Wh_r + 196608;
  const float* bx0 = bx_l;  const float* bx1 = bx_l + 256; const float* bx2 = bx_l + 512;
  const float* bh0 = bh_l;  const float* bh1 = bh_l + 256;
  const float* bh2 = bh_l + 512; const float* bh3 = bh_l + 768;

  const int eb  = (E + 255)/256;
  const int nb4 = (N + 3)/4;

  // ---- CSR build ----
  hipMemsetAsync(deg_i, 0, (size_t)N*4, stream);
  hipMemsetAsync(cursor, 0, (size_t)N*4, stream);
  detect_kernel<<<1,256,0,stream>>>(ei, flag);
  count_kernel<<<eb,256,0,stream>>>(ei, flag, deg_i, E);
  scan_kernel<<<1,1024,0,stream>>>(deg_i, row_ptr, inv_deg, N);
  fill_kernel<<<eb,256,0,stream>>>(ei, flag, row_ptr, cursor, col_src, E);

  // ---- constant rows ----
  rowprep_kernel<<<1,256,0,stream>>>(bh_l, bb1, bb2, Wb2, Wh_l, Wh_r,
                                     hrow, rowL1, rowR1, rowL2, rowR2);

  // ---- layer 1 (h = 0 specialization) ----
  aggregate_kernel<<<nb4,256,0,stream>>>(x, B0, row_ptr, col_src, inv_deg, N);  // aggx -> B0 (persists)
  // t1 = sigmoid(aggx@Wxl0 + x@Wxr0 + bx0 + g*rowL1 + rowR1) * hrow
  launch_gemm(1, B0,Wxl0, x,Wxr0, NUL,NUL, NUL,NUL, bx0,NUL, NUL,NUL,0,
              rowL1,rowR1, hrow,NUL, deg_i, B1, N, stream);
  // z1 = sigmoid(aggx@Wxl1 + x@Wxr1 + bx1 + g*rowL2 + rowR2)
  launch_gemm(1, B0,Wxl1, x,Wxr1, NUL,NUL, NUL,NUL, bx1,NUL, NUL,NUL,0,
              rowL2,rowR2, NUL,NUL, deg_i, B2, N, stream);
  aggregate_kernel<<<nb4,256,0,stream>>>(B1, B3, row_ptr, col_src, inv_deg, N); // agg(t1) -> B3
  // h1 = (1-z1)*hrow + z1*tanh(agg_t1@Whl3 + t1@Whr3 + aggx@Wxl2 + x@Wxr2 + bx2 + bh3)
  launch_gemm(3, B3,Whl3, B1,Whr3, B0,Wxl2, x,Wxr2, bx2,bh3, B2,hrow,1,
              NUL,NUL, NUL,NUL, NULI, H, N, stream);

  // ---- layer 2 ----
  aggregate_kernel<<<nb4,256,0,stream>>>(H, B1, row_ptr, col_src, inv_deg, N);  // agg(h1) -> B1
  // h_N = agg_h1@Whl0 + h1@Whr0 + bh0
  launch_gemm(0, B1,Whl0, H,Whr0, NUL,NUL, NUL,NUL, bh0,NUL, NUL,NUL,0,
              NUL,NUL, NUL,NUL, NULI, B2, N, stream);
  // hN2 = h1 + tanh(h1@Wb1 + h_N@Wb2 + bb1 + bb2)
  launch_gemm(2, H,Wb1, B2,Wb2, NUL,NUL, NUL,NUL, bb1,bb2, NUL,H,0,
              NUL,NUL, NUL,NUL, NULI, B3, N, stream);
  aggregate_kernel<<<nb4,256,0,stream>>>(B3, B1, row_ptr, col_src, inv_deg, N); // agg(hN2) -> B1
  // t2 = sigmoid(agg@Whl1 + hN2@Whr1 + aggx@Wxl0 + x@Wxr0 + bx0 + bh1) * hN2
  launch_gemm(1, B1,Whl1, B3,Whr1, B0,Wxl0, x,Wxr0, bx0,bh1, NUL,NUL,0,
              NUL,NUL, NUL,B3, NULI, B2, N, stream);
  // z2 = sigmoid(agg@Whl2 + hN2@Whr2 + aggx@Wxl1 + x@Wxr1 + bx1 + bh2) -> H (h1 dead)
  launch_gemm(1, B1,Whl2, B3,Whr2, B0,Wxl1, x,Wxr1, bx1,bh2, NUL,NUL,0,
              NUL,NUL, NUL,NUL, NULI, H, N, stream);
  aggregate_kernel<<<nb4,256,0,stream>>>(B2, B1, row_ptr, col_src, inv_deg, N); // agg(t2) -> B1
  // h2 = (1-z2)*hN2 + z2*tanh(agg_t2@Whl3 + t2@Whr3 + aggx@Wxl2 + x@Wxr2 + bx2 + bh3)
  launch_gemm(3, B1,Whl3, B2,Whr3, B0,Wxl2, x,Wxr2, bx2,bh3, H,B3,0,
              NUL,NUL, NUL,NUL, NULI, H, N, stream);                 // Z in-place: safe (same-thread idx)

  // ---- edge head ----
  launch_gemm(0, H,We1, NUL,NUL, NUL,NUL, NUL,NUL, be1,NUL, NUL,NUL,0,
              NUL,NUL, NUL,NUL, NULI, B0, N, stream);                // P = h2@We1_top + be1
  launch_gemm(0, H,We1+65536, NUL,NUL, NUL,NUL, NUL,NUL, NUL,NUL, NUL,NUL,0,
              NUL,NUL, NUL,NUL, NULI, B1, N, stream);                // Q = h2@We1_bot
  edge_pred_kernel<<<(E+3)/4,256,0,stream>>>(B0, B1, ei, flag, We2, be2, preds, E);
}

// Round 4
// 1365.919 us; speedup vs baseline: 2.7409x; 2.7409x over previous
//
#include <hip/hip_runtime.h>
#include <math.h>

#define HID 256

typedef __bf16 bf16x8 __attribute__((ext_vector_type(8)));
typedef float  f32x4  __attribute__((ext_vector_type(4)));

__device__ __forceinline__ float sigmoidf_(float x){ return 1.0f/(1.0f + __expf(-x)); }
__device__ __forceinline__ unsigned short f2b(float f){
  __bf16 b = (__bf16)f; return __builtin_bit_cast(unsigned short, b);
}
__device__ __forceinline__ float b2f(unsigned short u){
  return (float)__builtin_bit_cast(__bf16, u);
}

// ---- edge index access: handles both int32 and int64 on-disk storage ----
__device__ __forceinline__ int edge_src(const int* ei, int e, int is64){
  return is64 ? ei[2*e] : ei[e];
}
__device__ __forceinline__ int edge_dst(const int* ei, int e, int E, int is64){
  return is64 ? ei[2*(E+e)] : ei[E+e];
}

__global__ void detect_kernel(const int* __restrict__ ei, int* __restrict__ flag){
  __shared__ int any;
  if (threadIdx.x == 0) any = 0;
  __syncthreads();
  if (ei[2*threadIdx.x + 1] != 0) atomicOr(&any, 1);
  __syncthreads();
  if (threadIdx.x == 0) *flag = any ? 0 : 1;   // 1 -> int64 storage
}

__global__ void count_kernel(const int* __restrict__ ei, const int* __restrict__ flag,
                             int* __restrict__ deg_i, int E){
  int e = blockIdx.x*blockDim.x + threadIdx.x;
  if (e >= E) return;
  int is64 = *flag;
  atomicAdd(&deg_i[edge_dst(ei,e,E,is64)], 1);
}

__global__ __launch_bounds__(1024) void scan_kernel(const int* __restrict__ deg_i,
  int* __restrict__ row_ptr, float* __restrict__ inv_deg, int N)
{
  __shared__ int wsum[16];
  __shared__ int carry_s;
  int tid = threadIdx.x, lane = tid & 63, wid = tid >> 6;
  if (tid == 0) carry_s = 0;
  __syncthreads();
  for (int base = 0; base < N; base += 1024){
    int i = base + tid;
    int v = (i < N) ? deg_i[i] : 0;
    int s = v;
    #pragma unroll
    for (int off = 1; off < 64; off <<= 1){
      int t = __shfl_up(s, off, 64);
      if (lane >= off) s += t;
    }
    if (lane == 63) wsum[wid] = s;
    __syncthreads();
    if (tid == 0){
      int run = 0;
      for (int w2 = 0; w2 < 16; ++w2){ int t = wsum[w2]; wsum[w2] = run; run += t; }
    }
    __syncthreads();
    int excl = carry_s + wsum[wid] + s - v;
    if (i < N){
      row_ptr[i] = excl;
      inv_deg[i] = 1.0f / fmaxf((float)v, 1.0f);
    }
    __syncthreads();
    if (tid == 1023) carry_s = excl + v;
    __syncthreads();
  }
  if (threadIdx.x == 0) row_ptr[N] = carry_s;
}

__global__ void fill_kernel(const int* __restrict__ ei, const int* __restrict__ flag,
                            const int* __restrict__ row_ptr, int* __restrict__ cursor,
                            int* __restrict__ col_src, int E){
  int e = blockIdx.x*blockDim.x + threadIdx.x;
  if (e >= E) return;
  int is64 = *flag;
  int d = edge_dst(ei,e,E,is64);
  int pos = atomicAdd(&cursor[d], 1);
  col_src[row_ptr[d] + pos] = edge_src(ei,e,is64);
}

// f32 -> bf16 conversion (vector of 4)
__global__ __launch_bounds__(256) void conv_kernel(const float* __restrict__ in,
                                                   unsigned short* __restrict__ out, int n4){
  int i = blockIdx.x*256 + threadIdx.x;
  if (i >= n4) return;
  float4 v = *(const float4*)&in[(size_t)i*4];
  ushort4 o; o.x=f2b(v.x); o.y=f2b(v.y); o.z=f2b(v.z); o.w=f2b(v.w);
  *(ushort4*)&out[(size_t)i*4] = o;
}

// weights: f32 [K][N] row-major -> bf16 [N][K] (transposed), 18 slabs of 256x256
__global__ __launch_bounds__(256) void wconv_kernel(
  const float* __restrict__ Wx_l, const float* __restrict__ Wx_r,
  const float* __restrict__ Wh_l, const float* __restrict__ Wh_r,
  const float* __restrict__ Wb1,  const float* __restrict__ Wb2,
  const float* __restrict__ We1,  unsigned short* __restrict__ Wt)
{
  int widx = blockIdx.x;       // 0..17
  int n = blockIdx.y;          // 0..255 (output row = W column)
  int k = threadIdx.x;         // 0..255
  const float* src;
  if      (widx < 3)  src = Wx_l + widx*65536;
  else if (widx < 6)  src = Wx_r + (widx-3)*65536;
  else if (widx < 10) src = Wh_l + (widx-6)*65536;
  else if (widx < 14) src = Wh_r + (widx-10)*65536;
  else if (widx == 14) src = Wb1;
  else if (widx == 15) src = Wb2;
  else                src = We1 + (widx-16)*65536;
  Wt[(size_t)widx*65536 + n*256 + k] = f2b(src[k*256 + n]);
}

// mean aggregation over bf16 features: one wave per node, ushort4 per lane
__global__ __launch_bounds__(256) void aggregate_b_kernel(
    const unsigned short* __restrict__ X, unsigned short* __restrict__ out,
    const int* __restrict__ row_ptr, const int* __restrict__ col_src,
    const float* __restrict__ inv_deg, int N)
{
  int v = blockIdx.x*4 + (threadIdx.x >> 6);
  int lane = threadIdx.x & 63;
  if (v >= N) return;
  int beg = row_ptr[v], end = row_ptr[v+1];
  float a0=0.f, a1=0.f, a2=0.f, a3=0.f;
  int e = beg;
  for (; e + 4 <= end; e += 4){
    int s0 = col_src[e], s1 = col_src[e+1], s2 = col_src[e+2], s3 = col_src[e+3];
    ushort4 u0 = *(const ushort4*)&X[(size_t)s0*HID + lane*4];
    ushort4 u1 = *(const ushort4*)&X[(size_t)s1*HID + lane*4];
    ushort4 u2 = *(const ushort4*)&X[(size_t)s2*HID + lane*4];
    ushort4 u3 = *(const ushort4*)&X[(size_t)s3*HID + lane*4];
    a0 += b2f(u0.x)+b2f(u1.x)+b2f(u2.x)+b2f(u3.x);
    a1 += b2f(u0.y)+b2f(u1.y)+b2f(u2.y)+b2f(u3.y);
    a2 += b2f(u0.z)+b2f(u1.z)+b2f(u2.z)+b2f(u3.z);
    a3 += b2f(u0.w)+b2f(u1.w)+b2f(u2.w)+b2f(u3.w);
  }
  for (; e < end; ++e){
    int s0 = col_src[e];
    ushort4 u0 = *(const ushort4*)&X[(size_t)s0*HID + lane*4];
    a0 += b2f(u0.x); a1 += b2f(u0.y); a2 += b2f(u0.z); a3 += b2f(u0.w);
  }
  float w = inv_deg[v];
  ushort4 o; o.x=f2b(a0*w); o.y=f2b(a1*w); o.z=f2b(a2*w); o.w=f2b(a3*w);
  *(ushort4*)&out[(size_t)v*HID + lane*4] = o;
}

// layer-1 constant rows (f32): hrow = tanh(bb1+bb2+bh0@Wb2); rowL/rowR for r,z
__global__ __launch_bounds__(256) void rowprep_kernel(
  const float* __restrict__ bh_l, const float* __restrict__ bb1, const float* __restrict__ bb2,
  const float* __restrict__ Wb2, const float* __restrict__ Wh_l, const float* __restrict__ Wh_r,
  float* __restrict__ hrow, float* __restrict__ rowL1, float* __restrict__ rowR1,
  float* __restrict__ rowL2, float* __restrict__ rowR2)
{
  __shared__ float sh[256];
  __shared__ float sh2[256];
  int j = threadIdx.x;
  sh[j] = bh_l[j];                       // bh_l[0]
  __syncthreads();
  float acc = bb1[j] + bb2[j];
  for (int k = 0; k < 256; ++k) acc = fmaf(sh[k], Wb2[k*256 + j], acc);
  float hr = tanhf(acc);
  hrow[j] = hr; sh2[j] = hr;
  __syncthreads();
  const float* Whl1 = Wh_l + 65536;  const float* Whr1 = Wh_r + 65536;
  const float* Whl2 = Wh_l + 131072; const float* Whr2 = Wh_r + 131072;
  float a1=0.f, b1=0.f, a2=0.f, b2v=0.f;
  for (int k = 0; k < 256; ++k){
    float hv = sh2[k];
    a1  = fmaf(hv, Whl1[k*256+j], a1);
    b1  = fmaf(hv, Whr1[k*256+j], b1);
    a2  = fmaf(hv, Whl2[k*256+j], a2);
    b2v = fmaf(hv, Whr2[k*256+j], b2v);
  }
  rowL1[j] = a1; rowR1[j] = b1 + bh_l[256 + j];
  rowL2[j] = a2; rowR2[j] = b2v + bh_l[512 + j];
}

// MFMA GEMM: out = epilogue(sum_i Ai@Wi^T + bias + bias2)
// Ai: bf16 [M][256]; Wi: bf16 [256(n)][256(k)] (pre-transposed weights)
// MODE 0 LIN, 1 SIG (*mulrow/*mulmat, +g*rowA+rowB), 2 TANHADD (HN[idx]+tanh), 3 GRU
template<int MODE>
__global__ __launch_bounds__(256) void mgemm_kernel(
    const unsigned short* __restrict__ A0, const unsigned short* __restrict__ W0,
    const unsigned short* __restrict__ A1, const unsigned short* __restrict__ W1,
    const unsigned short* __restrict__ A2, const unsigned short* __restrict__ W2,
    const unsigned short* __restrict__ A3, const unsigned short* __restrict__ W3,
    const float* __restrict__ bias, const float* __restrict__ bias2,
    const float* Z, const float* HN, int hn_bcast,
    const float* __restrict__ rowA, const float* __restrict__ rowB,
    const float* __restrict__ mulrow, const float* mulmat,
    const int* __restrict__ deg,
    float* outF, unsigned short* outB, int M)
{
  __shared__ unsigned short Al[128*32];
  __shared__ unsigned short Bl[128*32];
  const int tid  = threadIdx.x;
  const int lane = tid & 63, w = tid >> 6;
  const int wr = w >> 1, wc = w & 1;
  const int lane15 = lane & 15, laneq = (lane >> 4) * 8;
  const int row0 = blockIdx.x * 128, col0 = blockIdx.y * 128;

  f32x4 acc[4][4];
  #pragma unroll
  for (int m = 0; m < 4; ++m)
    #pragma unroll
    for (int n = 0; n < 4; ++n) acc[m][n] = (f32x4)0.f;

  // compact pass list
  const unsigned short* pa[4]; const unsigned short* pw[4];
  int np = 0;
  if (A0){ pa[np]=A0; pw[np]=W0; ++np; }
  if (A1){ pa[np]=A1; pw[np]=W1; ++np; }
  if (A2){ pa[np]=A2; pw[np]=W2; ++np; }
  if (A3){ pa[np]=A3; pw[np]=W3; ++np; }
  const int steps = np * 8;            // K=256, BK=32

  // staging geometry: thread t covers LDS row t>>1, k-offset (t&1)*16 .. +16
  const int srow = tid >> 1;
  const int koff = (tid & 1) * 16;
  const int arow = (row0 + srow > M-1) ? (M-1) : (row0 + srow);  // clamp OOB rows

  uint4 ra0, ra1, rb0, rb1;
  {
    const unsigned short* Ap = pa[0];
    const unsigned short* Wp = pw[0];
    const unsigned short* ga = Ap + (size_t)arow*HID + koff;
    const unsigned short* gb = Wp + (size_t)(col0 + srow)*HID + koff;
    ra0 = *(const uint4*)(ga);  ra1 = *(const uint4*)(ga + 8);
    rb0 = *(const uint4*)(gb);  rb1 = *(const uint4*)(gb + 8);
  }

  for (int s = 0; s < steps; ++s){
    __syncthreads();
    *(uint4*)&Al[tid*16]     = ra0;
    *(uint4*)&Al[tid*16 + 8] = ra1;
    *(uint4*)&Bl[tid*16]     = rb0;
    *(uint4*)&Bl[tid*16 + 8] = rb1;
    if (s + 1 < steps){
      int sp = s + 1;
      const unsigned short* Ap = pa[sp >> 3];
      const unsigned short* Wp = pw[sp >> 3];
      int k0 = (sp & 7) * 32;
      const unsigned short* ga = Ap + (size_t)arow*HID + k0 + koff;
      const unsigned short* gb = Wp + (size_t)(col0 + srow)*HID + k0 + koff;
      ra0 = *(const uint4*)(ga);  ra1 = *(const uint4*)(ga + 8);
      rb0 = *(const uint4*)(gb);  rb1 = *(const uint4*)(gb + 8);
    }
    __syncthreads();

    bf16x8 af[4], bfr[4];
    #pragma unroll
    for (int m = 0; m < 4; ++m)
      af[m] = *(const bf16x8*)&Al[(wr*64 + m*16 + lane15)*32 + laneq];
    #pragma unroll
    for (int n = 0; n < 4; ++n)
      bfr[n] = *(const bf16x8*)&Bl[(wc*64 + n*16 + lane15)*32 + laneq];
    #pragma unroll
    for (int m = 0; m < 4; ++m)
      #pragma unroll
      for (int n = 0; n < 4; ++n)
        acc[m][n] = __builtin_amdgcn_mfma_f32_16x16x32_bf16(af[m], bfr[n], acc[m][n], 0, 0, 0);
  }

  // epilogue: D[row][col]: col = lane&15, row = (lane>>4)*4 + r
  #pragma unroll
  for (int n = 0; n < 4; ++n){
    int gc = col0 + wc*64 + n*16 + lane15;
    float badd = 0.f;
    if (bias)  badd += bias[gc];
    if (bias2) badd += bias2[gc];
    float rA = 0.f, rB = 0.f, mr = 1.f, hnb = 0.f;
    if (MODE == 1){
      if (rowA){ rA = rowA[gc]; rB = rowB[gc]; }
      if (mulrow) mr = mulrow[gc];
    }
    if (MODE == 3 && hn_bcast) hnb = HN[gc];
    #pragma unroll
    for (int m = 0; m < 4; ++m){
      int rb = row0 + wr*64 + m*16 + ((lane >> 4) << 2);
      #pragma unroll
      for (int r = 0; r < 4; ++r){
        int gr = rb + r;
        if (gr >= M) continue;
        size_t idx = (size_t)gr*HID + gc;
        float p = acc[m][n][r] + badd;
        float v;
        if (MODE == 0) v = p;
        else if (MODE == 1){
          float g = (rowA && deg) ? ((deg[gr] > 0) ? 1.f : 0.f) : 0.f;
          v = sigmoidf_(p + g*rA + rB);
          if (mulrow) v *= mr;
          if (mulmat) v *= mulmat[idx];
        } else if (MODE == 2){
          v = HN[idx] + tanhf(p);
        } else {
          float z  = Z[idx];
          float hv = hn_bcast ? hnb : HN[idx];
          v = (1.f - z)*hv + z*tanhf(p);
        }
        if (outF) outF[idx] = v;
        if (outB) outB[idx] = f2b(v);
      }
    }
  }
}

// per-edge: preds = sigmoid(relu(P[s]+Q[d]) . We2 + be2); be1 folded into P
__global__ __launch_bounds__(256) void edge_pred_kernel(
  const unsigned short* __restrict__ P, const unsigned short* __restrict__ Q,
  const int* __restrict__ ei, const int* __restrict__ flag,
  const float* __restrict__ We2, const float* __restrict__ be2,
  float* __restrict__ preds, int E)
{
  int wid = blockIdx.x*4 + (threadIdx.x >> 6);
  int lane = threadIdx.x & 63;
  if (wid >= E) return;
  int is64 = *flag;
  int s = edge_src(ei, wid, is64);
  int d = edge_dst(ei, wid, E, is64);
  ushort4 p4 = *(const ushort4*)&P[(size_t)s*HID + lane*4];
  ushort4 q4 = *(const ushort4*)&Q[(size_t)d*HID + lane*4];
  float4 w = *(const float4*)&We2[lane*4];
  float h0 = fmaxf(b2f(p4.x) + b2f(q4.x), 0.f);
  float h1 = fmaxf(b2f(p4.y) + b2f(q4.y), 0.f);
  float h2 = fmaxf(b2f(p4.z) + b2f(q4.z), 0.f);
  float h3 = fmaxf(b2f(p4.w) + b2f(q4.w), 0.f);
  float part = h0*w.x + h1*w.y + h2*w.z + h3*w.w;
  #pragma unroll
  for (int off = 32; off > 0; off >>= 1) part += __shfl_down(part, off, 64);
  if (lane == 0) preds[wid] = sigmoidf_(part + be2[0]);
}

typedef const unsigned short* cus;
typedef const float* cf;

static void launch_mg(int mode,
  cus A0, cus W0, cus A1, cus W1, cus A2, cus W2, cus A3, cus W3,
  cf bias, cf bias2, cf Z, cf HN, int hn_bcast,
  cf rowA, cf rowB, cf mulrow, cf mulmat, const int* deg,
  float* outF, unsigned short* outB, int M, hipStream_t s)
{
  dim3 g((M + 127)/128, 2), b(256);
  switch (mode){
    case 0: mgemm_kernel<0><<<g,b,0,s>>>(A0,W0,A1,W1,A2,W2,A3,W3,bias,bias2,Z,HN,hn_bcast,rowA,rowB,mulrow,mulmat,deg,outF,outB,M); break;
    case 1: mgemm_kernel<1><<<g,b,0,s>>>(A0,W0,A1,W1,A2,W2,A3,W3,bias,bias2,Z,HN,hn_bcast,rowA,rowB,mulrow,mulmat,deg,outF,outB,M); break;
    case 2: mgemm_kernel<2><<<g,b,0,s>>>(A0,W0,A1,W1,A2,W2,A3,W3,bias,bias2,Z,HN,hn_bcast,rowA,rowB,mulrow,mulmat,deg,outF,outB,M); break;
    default:mgemm_kernel<3><<<g,b,0,s>>>(A0,W0,A1,W1,A2,W2,A3,W3,bias,bias2,Z,HN,hn_bcast,rowA,rowB,mulrow,mulmat,deg,outF,outB,M); break;
  }
}

extern "C" void kernel_launch(void* const* d_in, const int* in_sizes, int n_in,
                              void* d_out, int out_size, void* d_ws, size_t ws_size,
                              hipStream_t stream)
{
  const float* x    = (const float*)d_in[0];
  const int*   ei   = (const int*)  d_in[1];
  const float* Wx_l = (const float*)d_in[2];
  const float* bx_l = (const float*)d_in[3];
  const float* Wx_r = (const float*)d_in[4];
  const float* Wh_l = (const float*)d_in[5];
  const float* bh_l = (const float*)d_in[6];
  const float* Wh_r = (const float*)d_in[7];
  const float* Wb1  = (const float*)d_in[8];
  const float* bb1  = (const float*)d_in[9];
  const float* Wb2  = (const float*)d_in[10];
  const float* bb2  = (const float*)d_in[11];
  const float* We1  = (const float*)d_in[12];
  const float* be1  = (const float*)d_in[13];
  const float* We2  = (const float*)d_in[14];
  const float* be2  = (const float*)d_in[15];

  const int N = in_sizes[0] / HID;
  const int E = in_sizes[1] / 2;
  cf NUL = nullptr; cus NUB = nullptr; const int* NULI = nullptr;

  size_t off = 0;
  auto alloc = [&](size_t bytes) -> void* {
    void* p = (char*)d_ws + off;
    off += (bytes + 255) & ~(size_t)255;
    return p;
  };
  int*   deg_i   = (int*)  alloc((size_t)N*4);
  int*   cursor  = (int*)  alloc((size_t)N*4);
  int*   row_ptr = (int*)  alloc(((size_t)N+1)*4);
  int*   col_src = (int*)  alloc((size_t)E*4);
  float* inv_deg = (float*)alloc((size_t)N*4);
  int*   flag    = (int*)  alloc(256);
  float* hrow    = (float*)alloc(1024);
  float* rowL1   = (float*)alloc(1024);
  float* rowR1   = (float*)alloc(1024);
  float* rowL2   = (float*)alloc(1024);
  float* rowR2   = (float*)alloc(1024);
  unsigned short* Wt = (unsigned short*)alloc((size_t)18*65536*2);   // bf16 [n][k] weights
  float* F0 = (float*)alloc((size_t)N*HID*4);
  float* F1 = (float*)alloc((size_t)N*HID*4);
  unsigned short* b0 = (unsigned short*)alloc((size_t)N*HID*2);  // xb (persist)
  unsigned short* b1 = (unsigned short*)alloc((size_t)N*HID*2);  // aggxB (persist)
  unsigned short* b2 = (unsigned short*)alloc((size_t)N*HID*2);
  unsigned short* b3 = (unsigned short*)alloc((size_t)N*HID*2);
  unsigned short* b4 = (unsigned short*)alloc((size_t)N*HID*2);

  float* preds = (float*)d_out;
  float* H     = preds + E;          // final h2 (f32) output region

  auto WT = [&](int i) -> cus { return Wt + (size_t)i*65536; };
  // WT index map: Wxl_j=j, Wxr_j=3+j, Whl_j=6+j, Whr_j=10+j, Wb1=14, Wb2=15, We1top=16, We1bot=17
  const float* bx0 = bx_l;  const float* bx1 = bx_l + 256; const float* bx2 = bx_l + 512;
  const float* bh0 = bh_l;  const float* bh1 = bh_l + 256;
  const float* bh2 = bh_l + 512; const float* bh3 = bh_l + 768;

  const int eb  = (E + 255)/256;
  const int nb4 = (N + 3)/4;
  const int n4b = (N*64 + 255)/256;

  // ---- CSR build ----
  hipMemsetAsync(deg_i, 0, (size_t)N*4, stream);
  hipMemsetAsync(cursor, 0, (size_t)N*4, stream);
  detect_kernel<<<1,256,0,stream>>>(ei, flag);
  count_kernel<<<eb,256,0,stream>>>(ei, flag, deg_i, E);
  scan_kernel<<<1,1024,0,stream>>>(deg_i, row_ptr, inv_deg, N);
  fill_kernel<<<eb,256,0,stream>>>(ei, flag, row_ptr, cursor, col_src, E);

  // ---- conversions + constant rows ----
  conv_kernel<<<n4b,256,0,stream>>>(x, b0, N*64);                                 // xb
  wconv_kernel<<<dim3(18,256),256,0,stream>>>(Wx_l, Wx_r, Wh_l, Wh_r, Wb1, Wb2, We1, Wt);
  rowprep_kernel<<<1,256,0,stream>>>(bh_l, bb1, bb2, Wb2, Wh_l, Wh_r,
                                     hrow, rowL1, rowR1, rowL2, rowR2);

  // ---- layer 1 (h = 0 specialization) ----
  aggregate_b_kernel<<<nb4,256,0,stream>>>(b0, b1, row_ptr, col_src, inv_deg, N); // aggx -> b1
  // t1 = sigmoid(aggx@Wxl0 + x@Wxr0 + bx0 + g*rowL1 + rowR1) * hrow  -> b2 (bf16)
  launch_mg(1, b1,WT(0), b0,WT(3), NUB,NUB, NUB,NUB, bx0,NUL, NUL,NUL,0,
            rowL1,rowR1, hrow,NUL, deg_i, nullptr, b2, N, stream);
  // z1 = sigmoid(aggx@Wxl1 + x@Wxr1 + bx1 + g*rowL2 + rowR2)  -> F0 (f32)
  launch_mg(1, b1,WT(1), b0,WT(4), NUB,NUB, NUB,NUB, bx1,NUL, NUL,NUL,0,
            rowL2,rowR2, NUL,NUL, deg_i, F0, nullptr, N, stream);
  aggregate_b_kernel<<<nb4,256,0,stream>>>(b2, b3, row_ptr, col_src, inv_deg, N); // agg(t1) -> b3
  // h1 = (1-z1)*hrow + z1*tanh(agg_t1@Whl3 + t1@Whr3 + aggx@Wxl2 + x@Wxr2 + bx2+bh3) -> F0(f32,in-place), b4(bf16)
  launch_mg(3, b3,WT(9), b2,WT(13), b1,WT(2), b0,WT(5), bx2,bh3, F0,hrow,1,
            NUL,NUL, NUL,NUL, NULI, F0, b4, N, stream);

  // ---- layer 2 ----
  aggregate_b_kernel<<<nb4,256,0,stream>>>(b4, b2, row_ptr, col_src, inv_deg, N); // agg(h1) -> b2
  // hN = agg_h1@Whl0 + h1@Whr0 + bh0 -> b3 (bf16)
  launch_mg(0, b2,WT(6), b4,WT(10), NUB,NUB, NUB,NUB, bh0,NUL, NUL,NUL,0,
            NUL,NUL, NUL,NUL, NULI, nullptr, b3, N, stream);
  // hN2 = h1 + tanh(h1@Wb1 + hN@Wb2 + bb1+bb2) -> F1 (f32), b2 (bf16)
  launch_mg(2, b4,WT(14), b3,WT(15), NUB,NUB, NUB,NUB, bb1,bb2, NUL,F0,0,
            NUL,NUL, NUL,NUL, NULI, F1, b2, N, stream);
  aggregate_b_kernel<<<nb4,256,0,stream>>>(b2, b3, row_ptr, col_src, inv_deg, N); // agg(hN2) -> b3
  // t2 = sigmoid(agg@Whl1 + hN2@Whr1 + aggx@Wxl0 + x@Wxr0 + bx0+bh1) * hN2 -> b4
  launch_mg(1, b3,WT(7), b2,WT(11), b1,WT(0), b0,WT(3), bx0,bh1, NUL,NUL,0,
            NUL,NUL, NUL,F1, NULI, nullptr, b4, N, stream);
  // z2 = sigmoid(agg@Whl2 + hN2@Whr2 + aggx@Wxl1 + x@Wxr1 + bx1+bh2) -> F0 (f32)
  launch_mg(1, b3,WT(8), b2,WT(12), b1,WT(1), b0,WT(4), bx1,bh2, NUL,NUL,0,
            NUL,NUL, NUL,NUL, NULI, F0, nullptr, N, stream);
  aggregate_b_kernel<<<nb4,256,0,stream>>>(b4, b3, row_ptr, col_src, inv_deg, N); // agg(t2) -> b3
  // h2 = (1-z2)*hN2 + z2*tanh(agg_t2@Whl3 + t2@Whr3 + aggx@Wxl2 + x@Wxr2 + bx2+bh3) -> H (f32 out), b2 (bf16)
  launch_mg(3, b3,WT(9), b4,WT(13), b1,WT(2), b0,WT(5), bx2,bh3, F0,F1,0,
            NUL,NUL, NUL,NUL, NULI, H, b2, N, stream);

  // ---- edge head ----
  launch_mg(0, b2,WT(16), NUB,NUB, NUB,NUB, NUB,NUB, be1,NUL, NUL,NUL,0,
            NUL,NUL, NUL,NUL, NULI, nullptr, b3, N, stream);   // P = h2@We1_top + be1
  launch_mg(0, b2,WT(17), NUB,NUB, NUB,NUB, NUB,NUB, NUL,NUL, NUL,NUL,0,
            NUL,NUL, NUL,NUL, NULI, nullptr, b4, N, stream);   // Q = h2@We1_bot
  edge_pred_kernel<<<(E+3)/4,256,0,stream>>>(b3, b4, ei, flag, We2, be2, preds, E);
}